// Round 3
// baseline (26.205 us; speedup 1.0000x reference)
//
#include <hip/hip_runtime.h>
#include <hip/hip_bf16.h>
#include <math.h>

// Problem constants (mirror the reference module-level config)
#define IMG_H     256
#define IMG_W     256
#define BLK_H     8
#define BLK_W     8
#define N_BLOCKS  512
#define TILES     1024   // (256/8)*(256/8)
#define BATCH     32
#define GRID_W    32     // tiles per image row

typedef float f32x4 __attribute__((ext_vector_type(4)));  // native vector: OK for nontemporal builtins

// One 64-lane wave per (b, l) row: argmax over 512 logits+gumbel.
// 4 waves/block handle 4 adjacent tiles; the winning 8x8 blocks are staged in
// LDS and written out as fully-coalesced 128B row segments.
__global__ __launch_bounds__(256) void ImageReconstruction_55825984913931_kernel(
    const int*   __restrict__ frame_idxs,   // [BATCH]
    const float* __restrict__ sequence,     // [N_SEQ, TILES, N_BLOCKS]
    const float* __restrict__ blocks,       // [N_BLOCKS, 8, 8]
    const float* __restrict__ gumbel,       // [BATCH, TILES, N_BLOCKS]
    float*       __restrict__ out)          // [BATCH, 1, 256, 256]
{
    __shared__ float tilebuf[4][72];             // +8 pad: conflict-free read pattern

    const int wave = threadIdx.x >> 6;           // 4 waves per block
    const int lane = threadIdx.x & 63;
    const int row  = blockIdx.x * 4 + wave;      // [0, BATCH*TILES)
    const int b    = row >> 10;                  // / TILES
    const int l    = row & (TILES - 1);

    const int fi = frame_idxs[b];
    const float* __restrict__ seq_row = sequence + ((size_t)fi * TILES + l) * N_BLOCKS;
    const float* __restrict__ gum_row = gumbel   + ((size_t)b  * TILES + l) * N_BLOCKS;

    float best = -INFINITY;
    int   bidx = 0x7fffffff;

    // 512 elements = 2 chunks x 64 lanes x float4; coalesced 16B/lane loads.
    // Nontemporal: pure streaming data, keep it out of L2.
    #pragma unroll
    for (int c = 0; c < 2; ++c) {
        const int base = c * 256 + lane * 4;
        const f32x4 s = __builtin_nontemporal_load(
            reinterpret_cast<const f32x4*>(seq_row + base));
        const f32x4 g = __builtin_nontemporal_load(
            reinterpret_cast<const f32x4*>(gum_row + base));
        const float v[4] = { s.x + g.x, s.y + g.y, s.z + g.z, s.w + g.w };
        #pragma unroll
        for (int j = 0; j < 4; ++j) {
            // increasing index order + strict '>' keeps the earliest max
            if (v[j] > best) { best = v[j]; bidx = base + j; }
        }
    }

    // Butterfly reduce across the 64-lane wave; tie-break: lowest index.
    #pragma unroll
    for (int off = 32; off >= 1; off >>= 1) {
        const float ov = __shfl_xor(best, off, 64);
        const int   oi = __shfl_xor(bidx, off, 64);
        if (ov > best || (ov == best && oi < bidx)) { best = ov; bidx = oi; }
    }

    // Stage winning block (64 f32, blocks table is L2-resident: 128 KB).
    tilebuf[wave][lane] = blocks[bidx * (BLK_H * BLK_W) + lane];
    __syncthreads();

    // Cooperative write: 4 adjacent tiles (same tile-row, since blockIdx*4 is
    // 4-aligned) = 8 image rows x 128B contiguous. Thread t writes one pixel.
    const int t       = threadIdx.x;
    const int r_local = t >> 5;                  // 0..7  (row within tile)
    const int c       = t & 31;                  // 0..31 (col across 4 tiles)
    const int l0      = blockIdx.x * 4;          // first tile of this block
    const int b0      = l0 >> 10;
    const int ti      = (l0 & (TILES - 1)) >> 5; // tile row
    const int tj0     = l0 & (GRID_W - 1);       // first tile col (multiple of 4)

    const float val = tilebuf[c >> 3][r_local * 8 + (c & 7)];
    out[(size_t)b0 * (IMG_H * IMG_W) + (ti * BLK_H + r_local) * IMG_W + tj0 * BLK_W + c] = val;
}

extern "C" void kernel_launch(void* const* d_in, const int* in_sizes, int n_in,
                              void* d_out, int out_size, void* d_ws, size_t ws_size,
                              hipStream_t stream) {
    const int*   frame_idxs = (const int*)  d_in[0];
    const float* sequence   = (const float*)d_in[1];
    const float* blocks     = (const float*)d_in[2];
    const float* gumbel     = (const float*)d_in[3];
    float*       out        = (float*)      d_out;

    const int rows = BATCH * TILES;              // 32768 waves
    const int grid = rows / 4;                   // 4 waves (256 threads) per block
    ImageReconstruction_55825984913931_kernel<<<grid, 256, 0, stream>>>(
        frame_idxs, sequence, blocks, gumbel, out);
}